// Round 5
// baseline (124.144 us; speedup 1.0000x reference)
//
#include <hip/hip_runtime.h>
#include <stdint.h>

#define NN 4096
#define DD 512
#define NH 3
#define WMAX 64   // per-wave nonzero list; mean 10.2, sd 3.2 -> 16 sigma headroom

typedef float        f32x4 __attribute__((ext_vector_type(4)));
typedef float        f32x2 __attribute__((ext_vector_type(2)));
typedef unsigned int u32x4 __attribute__((ext_vector_type(4)));

__device__ __forceinline__ unsigned short f2bf_rn(float x) {
    union { float f; uint32_t u; } v; v.f = x;
    uint32_t u = v.u;
    uint32_t r = (u + 0x7FFFu + ((u >> 16) & 1u)) >> 16;
    return (unsigned short)r;
}
__device__ __forceinline__ float bflo(uint32_t u) {
    union { uint32_t u; float f; } v; v.u = u << 16; return v.f;
}
__device__ __forceinline__ float bfhi(uint32_t u) {
    union { uint32_t u; float f; } v; v.u = u & 0xFFFF0000u; return v.f;
}

// Kernel A: one wave per node j. w[j][h] = exp(relu(h[j]·P[:,h])); bf16 copy
// of h. h is read once -> non-temporal (don't evict hb/w from L2).
__global__ __launch_bounds__(256) void prep_kernel(
    const float* __restrict__ h, const float* __restrict__ P,
    float* __restrict__ w, unsigned short* __restrict__ hb)
{
    int gid = blockIdx.x * 256 + threadIdx.x;
    int row = gid >> 6, ln = gid & 63;
    const f32x4* h4 = (const f32x4*)(h + (size_t)row * DD);
    f32x4 va = __builtin_nontemporal_load(h4 + ln * 2);
    f32x4 vb = __builtin_nontemporal_load(h4 + ln * 2 + 1);
    float e[8] = { va.x, va.y, va.z, va.w, vb.x, vb.y, vb.z, vb.w };

    uint32_t pk0 = (uint32_t)f2bf_rn(e[0]) | ((uint32_t)f2bf_rn(e[1]) << 16);
    uint32_t pk1 = (uint32_t)f2bf_rn(e[2]) | ((uint32_t)f2bf_rn(e[3]) << 16);
    uint32_t pk2 = (uint32_t)f2bf_rn(e[4]) | ((uint32_t)f2bf_rn(e[5]) << 16);
    uint32_t pk3 = (uint32_t)f2bf_rn(e[6]) | ((uint32_t)f2bf_rn(e[7]) << 16);
    u32x4 pk; pk.x = pk0; pk.y = pk1; pk.z = pk2; pk.w = pk3;
    *(u32x4*)(hb + (size_t)row * DD + ln * 8) = pk;   // keep resident in L2

    int d0 = ln * 8;
    float a0 = 0.f, a1 = 0.f, a2 = 0.f;
    #pragma unroll
    for (int k = 0; k < 8; ++k) {
        float hv = e[k];
        const float* Pr = P + (size_t)(d0 + k) * NH;
        a0 = fmaf(hv, Pr[0], a0);
        a1 = fmaf(hv, Pr[1], a1);
        a2 = fmaf(hv, Pr[2], a2);
    }
    #pragma unroll
    for (int off = 32; off > 0; off >>= 1) {
        a0 += __shfl_down(a0, off);
        a1 += __shfl_down(a1, off);
        a2 += __shfl_down(a2, off);
    }
    if (ln == 0) {
        w[row * NH + 0] = expf(fmaxf(a0, 0.f));
        w[row * NH + 1] = expf(fmaxf(a1, 0.f));
        w[row * NH + 2] = expf(fmaxf(a2, 0.f));
    }
}

// Kernel B: one block (4 waves) per row. Wave-private ballot compaction,
// per-head gather with 2-deep load pipeline. Graph loads + out stores are
// non-temporal so the 64MB stream / 8MB out don't evict hb (4MB) from the
// per-XCD L2. Combine uses 12KB LDS (waves 2/3 RMW into waves 0/1 regions).
__global__ __launch_bounds__(256) void att_agg_kernel(
    const float* __restrict__ g, const unsigned short* __restrict__ hb,
    const float* __restrict__ w, float* __restrict__ out)
{
    __shared__ float s_part[2 * NH * DD];  // 12 KB: [wv01][h][col]
    __shared__ int   s_list[4 * WMAX];     // 1 KB wave-private lists
    __shared__ float s_z[4][NH];
    __shared__ int   s_cw[4];

    const int row = blockIdx.x, tid = threadIdx.x;
    const int wv = tid >> 6, ln = tid & 63;

    // ---- Phase A: scan own quarter (1024 floats), wave-private compaction ----
    const f32x4* g4 = (const f32x4*)(g + (size_t)row * NN) + wv * 256;
    f32x4 v0 = __builtin_nontemporal_load(g4 + ln);
    f32x4 v1 = __builtin_nontemporal_load(g4 + 64 + ln);
    f32x4 v2 = __builtin_nontemporal_load(g4 + 128 + ln);
    f32x4 v3 = __builtin_nontemporal_load(g4 + 192 + ln);

    int* mylist = s_list + wv * WMAX;
    int cbase = wv * 1024;
    int cnt = 0;
    f32x4 vs[4] = { v0, v1, v2, v3 };
    #pragma unroll
    for (int k = 0; k < 4; ++k) {
        float comp[4] = { vs[k].x, vs[k].y, vs[k].z, vs[k].w };
        int col0 = cbase + k * 256 + ln * 4;
        #pragma unroll
        for (int c = 0; c < 4; ++c) {
            bool p = comp[c] > 0.f;
            unsigned long long m = __ballot(p);
            if (p) {
                unsigned pre = __builtin_amdgcn_mbcnt_lo((unsigned)m, 0u);
                pre = __builtin_amdgcn_mbcnt_hi((unsigned)(m >> 32), pre);
                int pos = cnt + (int)pre;
                if (pos < WMAX) mylist[pos] = col0 + c;
            }
            cnt += __popcll(m);   // wave-uniform
        }
    }
    if (cnt > WMAX) cnt = WMAX;

    // ---- Phase B: gather own nonzeros, per-head accumulate (2-deep pipeline) ----
    float accA[8] = {0,0,0,0,0,0,0,0};
    float accB[8] = {0,0,0,0,0,0,0,0};
    float accC[8] = {0,0,0,0,0,0,0,0};
    float z0 = 0.f, z1 = 0.f, z2 = 0.f;
    const unsigned short* hcol = hb + ln * 8;

    u32x4 r0, r1;
    float wa0 = 0.f, wa1 = 0.f, wa2 = 0.f, wb0 = 0.f, wb1 = 0.f, wb2 = 0.f;
    if (cnt > 0) {
        int j = mylist[0];
        r0 = *(const u32x4*)(hcol + (size_t)j * DD);
        const float* wr = w + (size_t)j * NH;
        wa0 = wr[0]; wa1 = wr[1]; wa2 = wr[2];
    }
    if (cnt > 1) {
        int j = mylist[1];
        r1 = *(const u32x4*)(hcol + (size_t)j * DD);
        const float* wr = w + (size_t)j * NH;
        wb0 = wr[0]; wb1 = wr[1]; wb2 = wr[2];
    }
    for (int t = 0; t < cnt; ++t) {
        u32x4 r = r0;
        float c0 = wa0, c1 = wa1, c2 = wa2;
        r0 = r1; wa0 = wb0; wa1 = wb1; wa2 = wb2;
        if (t + 2 < cnt) {                 // wave-uniform
            int j2 = mylist[t + 2];
            r1 = *(const u32x4*)(hcol + (size_t)j2 * DD);
            const float* wr2 = w + (size_t)j2 * NH;
            wb0 = wr2[0]; wb1 = wr2[1]; wb2 = wr2[2];
        }
        z0 += c0; z1 += c1; z2 += c2;
        float e[8] = { bflo(r.x), bfhi(r.x), bflo(r.y), bfhi(r.y),
                       bflo(r.z), bfhi(r.z), bflo(r.w), bfhi(r.w) };
        #pragma unroll
        for (int q = 0; q < 8; ++q) {
            accA[q] = fmaf(c0, e[q], accA[q]);
            accB[q] = fmaf(c1, e[q], accB[q]);
            accC[q] = fmaf(c2, e[q], accC[q]);
        }
    }

    // ---- Combine: waves 0/1 write partials; waves 2/3 RMW-add; reduce ----
    if (ln == 0) { s_z[wv][0] = z0; s_z[wv][1] = z1; s_z[wv][2] = z2; s_cw[wv] = cnt; }
    if (wv < 2) {
        float* base = s_part + (wv * NH + 0) * DD + ln * 8;
        *(float4*)(base)     = make_float4(accA[0], accA[1], accA[2], accA[3]);
        *(float4*)(base + 4) = make_float4(accA[4], accA[5], accA[6], accA[7]);
        base = s_part + (wv * NH + 1) * DD + ln * 8;
        *(float4*)(base)     = make_float4(accB[0], accB[1], accB[2], accB[3]);
        *(float4*)(base + 4) = make_float4(accB[4], accB[5], accB[6], accB[7]);
        base = s_part + (wv * NH + 2) * DD + ln * 8;
        *(float4*)(base)     = make_float4(accC[0], accC[1], accC[2], accC[3]);
        *(float4*)(base + 4) = make_float4(accC[4], accC[5], accC[6], accC[7]);
    }
    __syncthreads();
    if (wv >= 2) {
        float* base = s_part + ((wv - 2) * NH + 0) * DD + ln * 8;
        float4 p0 = *(float4*)(base), p1 = *(float4*)(base + 4);
        p0.x += accA[0]; p0.y += accA[1]; p0.z += accA[2]; p0.w += accA[3];
        p1.x += accA[4]; p1.y += accA[5]; p1.z += accA[6]; p1.w += accA[7];
        *(float4*)(base) = p0; *(float4*)(base + 4) = p1;
        base = s_part + ((wv - 2) * NH + 1) * DD + ln * 8;
        p0 = *(float4*)(base); p1 = *(float4*)(base + 4);
        p0.x += accB[0]; p0.y += accB[1]; p0.z += accB[2]; p0.w += accB[3];
        p1.x += accB[4]; p1.y += accB[5]; p1.z += accB[6]; p1.w += accB[7];
        *(float4*)(base) = p0; *(float4*)(base + 4) = p1;
        base = s_part + ((wv - 2) * NH + 2) * DD + ln * 8;
        p0 = *(float4*)(base); p1 = *(float4*)(base + 4);
        p0.x += accC[0]; p0.y += accC[1]; p0.z += accC[2]; p0.w += accC[3];
        p1.x += accC[4]; p1.y += accC[5]; p1.z += accC[6]; p1.w += accC[7];
        *(float4*)(base) = p0; *(float4*)(base + 4) = p1;
    }
    __syncthreads();

    float Z0 = s_z[0][0] + s_z[1][0] + s_z[2][0] + s_z[3][0];
    float Z1 = s_z[0][1] + s_z[1][1] + s_z[2][1] + s_z[3][1];
    float Z2 = s_z[0][2] + s_z[1][2] + s_z[2][2] + s_z[3][2];
    int nnz = s_cw[0] + s_cw[1] + s_cw[2] + s_cw[3];

    int c0 = tid * 2;
    float sA0 = 0.f, sA1 = 0.f, sB0 = 0.f, sB1 = 0.f, sC0 = 0.f, sC1 = 0.f;
    #pragma unroll
    for (int W = 0; W < 2; ++W) {
        float2 pa = *(const float2*)(s_part + (W * NH + 0) * DD + c0);
        float2 pb = *(const float2*)(s_part + (W * NH + 1) * DD + c0);
        float2 pc = *(const float2*)(s_part + (W * NH + 2) * DD + c0);
        sA0 += pa.x; sA1 += pa.y;
        sB0 += pb.x; sB1 += pb.y;
        sC0 += pc.x; sC1 += pc.y;
    }
    f32x2 res;
    if (nnz == 0) {
        res.x = 0.f; res.y = 0.f;
    } else {
        float rs = (float)nnz;   // binary graph: rowsum == degree
        float i0 = rs / Z0, i1 = rs / Z1, i2 = rs / Z2;
        res.x = fmaf(sA0, i0, fmaf(sB0, i1, sC0 * i2));
        res.y = fmaf(sA1, i0, fmaf(sB1, i1, sC1 * i2));
    }
    __builtin_nontemporal_store(res, (f32x2*)(out + (size_t)row * DD) + tid);
}

extern "C" void kernel_launch(void* const* d_in, const int* in_sizes, int n_in,
                              void* d_out, int out_size, void* d_ws, size_t ws_size,
                              hipStream_t stream) {
    const float* g = (const float*)d_in[0];   // graph_info [N,N]
    const float* h = (const float*)d_in[1];   // h [N,D]
    const float* P = (const float*)d_in[2];   // P [D,H]
    float* out = (float*)d_out;               // [N,D] fp32

    // ws layout: w fp32 [N,3] @0 (48KB); hb bf16 [N,D] @64KB (4MB)
    float* w           = (float*)d_ws;
    unsigned short* hb = (unsigned short*)((char*)d_ws + (64 << 10));

    prep_kernel<<<(NN * 64) / 256, 256, 0, stream>>>(h, P, w, hb);
    att_agg_kernel<<<NN, 256, 0, stream>>>(g, hb, w, out);
}